// Round 2
// baseline (383.077 us; speedup 1.0000x reference)
//
#include <hip/hip_runtime.h>
#include <stdint.h>

#define NUM_CAP 16
#define DIM_CAP 64
#define BATCH   64
#define N_IN    512
#define D_IN    1024
#define N_COL   1024                 // NUM_CAP*DIM_CAP
#define M_ROWS  (BATCH*N_IN)         // 32768

#define LDA 40                       // lA row stride (shorts): 80 B, 16B-aligned, breaks bank conflicts
#define LDB 32                       // lB row stride (shorts): required dense for global_load_lds

typedef __attribute__((ext_vector_type(8))) short short8;
typedef __attribute__((ext_vector_type(4))) float f32x4;

__device__ __forceinline__ float bf2f(unsigned int u) {
  return __uint_as_float(u << 16);
}
__device__ __forceinline__ unsigned short f2bf_rne(float f) {
  unsigned int x = __float_as_uint(f);
  x += 0x7fffu + ((x >> 16) & 1u);   // RNE
  return (unsigned short)(x >> 16);
}
// truncate two fp32 (bit patterns) to packed bf16x2 (lo in low half)
__device__ __forceinline__ unsigned int pack_trunc(unsigned int lo, unsigned int hi) {
  return (lo >> 16) | (hi & 0xffff0000u);
}

// ---------------------------------------------------------------------------
// W fp32 [D_IN][N_COL] -> Wt bf16 [N_COL][D_IN]  (transpose + RNE convert)
// ---------------------------------------------------------------------------
__global__ void transpose_w(const float* __restrict__ W,
                            unsigned short* __restrict__ Wt) {
  __shared__ float tile[32][33];
  const int tx = threadIdx.x, ty = threadIdx.y;
  const int bx = blockIdx.x, by = blockIdx.y;
  tile[ty][tx] = W[(by * 32 + ty) * N_COL + bx * 32 + tx];
  __syncthreads();
  Wt[(bx * 32 + ty) * D_IN + by * 32 + tx] = f2bf_rne(tile[tx][ty]);
}

// ---------------------------------------------------------------------------
// GEMM: uhat[m][n] = sum_k x[m][k] * Wt[n][k].  x fp32 (converted to bf16
// in-register during staging), Wt bf16 (global_load_lds width=16), fp32 acc,
// bf16 out. 128x128 tile, BK=32, 4 waves (2x2), 4x4 of 16x16x32 MFMA each.
// ---------------------------------------------------------------------------
__global__ __launch_bounds__(256) void gemm_uhat(
    const float* __restrict__ A,             // [M_ROWS][D_IN] fp32
    const unsigned short* __restrict__ Bt,   // [N_COL][D_IN] bf16
    unsigned short* __restrict__ C) {        // [M_ROWS][N_COL] bf16
  __shared__ __align__(16) unsigned short lA[128 * LDA];
  __shared__ __align__(16) unsigned short lB[128 * LDB];

  const int t = threadIdx.x;
  const int wave = t >> 6, lane = t & 63;
  const int mt = blockIdx.x >> 3, nt = blockIdx.x & 7;
  const int m0 = mt * 128, n0 = nt * 128;
  const int wm = wave & 1, wn = wave >> 1;

  f32x4 acc[4][4] = {};

  // A staging: thread t owns row ar=t>>1, k-halftile ah=t&1 (16 fp32 = 64B)
  const int ar = t >> 1, ah = t & 1;
  const float* agp = A + (size_t)(m0 + ar) * D_IN + ah * 16;
  unsigned short* lap = lA + ar * LDA + ah * 16;   // byte off = 80*ar+32*ah (16B-aligned)

  // B staging: global_load_lds — lane l -> lds base + l*16B (dense rows req'd)
  const int srow = lane >> 2;          // row within 16-row segment
  const int schunk = (lane & 3) * 8;   // 16B chunk within 64B row

  for (int kt = 0; kt < D_IN / 32; ++kt) {
    const int k0 = kt * 32;
    __syncthreads();
    // ---- A: 16 fp32 -> 16 bf16 (truncate) -> 2x ds_write_b128
    const uint4 a0 = *(const uint4*)(agp + k0);
    const uint4 a1 = *(const uint4*)(agp + k0 + 4);
    const uint4 a2 = *(const uint4*)(agp + k0 + 8);
    const uint4 a3 = *(const uint4*)(agp + k0 + 12);
    uint4 p0, p1;
    p0.x = pack_trunc(a0.x, a0.y); p0.y = pack_trunc(a0.z, a0.w);
    p0.z = pack_trunc(a1.x, a1.y); p0.w = pack_trunc(a1.z, a1.w);
    p1.x = pack_trunc(a2.x, a2.y); p1.y = pack_trunc(a2.z, a2.w);
    p1.z = pack_trunc(a3.x, a3.y); p1.w = pack_trunc(a3.z, a3.w);
    *(uint4*)lap       = p0;
    *(uint4*)(lap + 8) = p1;
    // ---- B: async global->LDS, 8 segments of 16 rows, 2 per wave
    #pragma unroll
    for (int s0 = 0; s0 < 2; ++s0) {
      const int s = wave + s0 * 4;
      const unsigned short* gb = Bt + (size_t)(n0 + s * 16 + srow) * D_IN + k0 + schunk;
      __builtin_amdgcn_global_load_lds(
          (const __attribute__((address_space(1))) void*)gb,
          (__attribute__((address_space(3))) void*)(lB + s * 16 * LDB), 16, 0, 0);
    }
    __syncthreads();   // compiler drains vmcnt+lgkmcnt before s_barrier

    short8 af[4], bfr[4];
    const int rsel = lane & 15;
    const int koff = (lane >> 4) * 8;  // A/B operand: outer=lane&15, k=quad*8+j
    #pragma unroll
    for (int tm = 0; tm < 4; tm++)
      af[tm] = *(const short8*)&lA[(wm * 64 + tm * 16 + rsel) * LDA + koff];
    #pragma unroll
    for (int tn = 0; tn < 4; tn++)
      bfr[tn] = *(const short8*)&lB[(wn * 64 + tn * 16 + rsel) * LDB + koff];
    #pragma unroll
    for (int tm = 0; tm < 4; tm++)
      #pragma unroll
      for (int tn = 0; tn < 4; tn++)
        acc[tm][tn] = __builtin_amdgcn_mfma_f32_16x16x32_bf16(
            af[tm], bfr[tn], acc[tm][tn], 0, 0, 0);
  }

  // Epilogue: C/D layout col=lane&15, row=(lane>>4)*4+reg  [m89-verified]
  const int lrow = (lane >> 4) * 4, lcol = lane & 15;
  #pragma unroll
  for (int tm = 0; tm < 4; tm++)
    #pragma unroll
    for (int tn = 0; tn < 4; tn++)
      #pragma unroll
      for (int r = 0; r < 4; r++) {
        const int row = m0 + wm * 64 + tm * 16 + lrow + r;
        const int col = n0 + wn * 64 + tn * 16 + lcol;
        C[(size_t)row * N_COL + col] = f2bf_rne(acc[tm][tn][r]);
      }
}

// ---------------------------------------------------------------------------
// Routing pass: block handles (b, jt4); wave w handles jt = jt4*4+w (8 j's).
// Per j: lane l holds u_hat[b, i=l>>2, j, k=(l&3)*16..+16] (contiguous 2KB row
// chunk, fully coalesced). dot with prev (quad shuffle), softmax over i
// (xor-{4,8,16,32} butterflies), accumulate c*u. Block-reduce 4 waves via LDS,
// write one fp32 slice P[b][jt4][i][k].
// ---------------------------------------------------------------------------
__global__ __launch_bounds__(256) void route_partial(
    const unsigned short* __restrict__ uhat,  // [M_ROWS][N_COL] bf16
    const float* __restrict__ prev,           // [BATCH][16][64] fp32
    float* __restrict__ P,                    // [BATCH][16][16][64] fp32
    const int first) {
  __shared__ float red[4][1024];
  const int t = threadIdx.x;
  const int w = t >> 6, lane = t & 63;
  const int b = blockIdx.x >> 4, jt4 = blockIdx.x & 15;
  const int jt = jt4 * 4 + w;                 // 0..63
  const int i_l = lane >> 2, c4 = lane & 3;

  float pv[16];
  if (!first) {
    const float* pp = prev + (b * NUM_CAP + i_l) * DIM_CAP + c4 * 16;
    #pragma unroll
    for (int q = 0; q < 16; q++) pv[q] = pp[q];
  }
  float acc[16];
  #pragma unroll
  for (int q = 0; q < 16; q++) acc[q] = 0.f;

  const unsigned short* ub =
      uhat + (size_t)(b * N_IN + jt * 8) * N_COL + lane * 16;

  for (int jj = 0; jj < 8; ++jj, ub += N_COL) {
    const uint4 d0 = *(const uint4*)ub;
    const uint4 d1 = *(const uint4*)(ub + 8);
    float u[16];
    #define UNP(wd, o) { u[(o)] = bf2f((wd) & 0xffffu); u[(o)+1] = __uint_as_float((wd) & 0xffff0000u); }
    UNP(d0.x, 0) UNP(d0.y, 2) UNP(d0.z, 4) UNP(d0.w, 6)
    UNP(d1.x, 8) UNP(d1.y, 10) UNP(d1.z, 12) UNP(d1.w, 14)
    #undef UNP

    float c;
    if (first) {
      c = 0.0625f;                    // softmax of zeros over 16 capsules
    } else {
      float dot = 0.f;
      #pragma unroll
      for (int q = 0; q < 16; q++) dot = fmaf(pv[q], u[q], dot);
      dot += __shfl_xor(dot, 1);      // reduce over k-quarters -> b_i on quad
      dot += __shfl_xor(dot, 2);
      float m = dot;
      #pragma unroll
      for (int d = 4; d < 64; d <<= 1) m = fmaxf(m, __shfl_xor(m, d));
      const float e = __expf(dot - m);
      float s = e;
      #pragma unroll
      for (int d = 4; d < 64; d <<= 1) s += __shfl_xor(s, d);
      c = e / s;
    }
    #pragma unroll
    for (int q = 0; q < 16; q++) acc[q] = fmaf(c, u[q], acc[q]);
  }

  // block reduce over the 4 waves
  #pragma unroll
  for (int q = 0; q < 4; q++)
    *(float4*)&red[w][lane * 16 + q * 4] = make_float4(
        acc[q * 4 + 0], acc[q * 4 + 1], acc[q * 4 + 2], acc[q * 4 + 3]);
  __syncthreads();
  const float4 r0 = *(const float4*)&red[0][t * 4];
  const float4 r1 = *(const float4*)&red[1][t * 4];
  const float4 r2 = *(const float4*)&red[2][t * 4];
  const float4 r3 = *(const float4*)&red[3][t * 4];
  float4 s;
  s.x = r0.x + r1.x + r2.x + r3.x;
  s.y = r0.y + r1.y + r2.y + r3.y;
  s.z = r0.z + r1.z + r2.z + r3.z;
  s.w = r0.w + r1.w + r2.w + r3.w;
  *(float4*)&P[(size_t)blockIdx.x * 1024 + t * 4] = s;
}

// ---------------------------------------------------------------------------
// Reduce partials over 16 jt4-slices + squash. One wave per (b,i).
// ---------------------------------------------------------------------------
__global__ __launch_bounds__(64) void route_reduce(
    const float* __restrict__ P, float* __restrict__ dst) {
  const int bi = blockIdx.x;          // b*16 + i
  const int k = threadIdx.x;          // 0..63
  const int b = bi >> 4, i = bi & 15;
  const float* p = P + (size_t)b * 16 * 1024 + i * 64 + k;
  float s = 0.f;
  #pragma unroll
  for (int tt = 0; tt < 16; ++tt) s += p[(size_t)tt * 1024];
  float ss = s * s;
  #pragma unroll
  for (int d = 1; d < 64; d <<= 1) ss += __shfl_xor(ss, d);
  dst[bi * 64 + k] = s / sqrtf(ss + 1e-7f);   // squash: v/sqrt(||v||^2+eps)
}

// ---------------------------------------------------------------------------
extern "C" void kernel_launch(void* const* d_in, const int* in_sizes, int n_in,
                              void* d_out, int out_size, void* d_ws, size_t ws_size,
                              hipStream_t stream) {
  const float* x = (const float*)d_in[0];   // [64][512][1024] fp32
  const float* W = (const float*)d_in[1];   // [1][1024][1024] fp32
  float* out = (float*)d_out;               // [64][16][64] fp32

  char* ws = (char*)d_ws;
  unsigned short* Wt   = (unsigned short*)ws;                        // 2 MB
  unsigned short* uhat = (unsigned short*)(ws + (size_t)(2 << 20));  // 64 MB
  float* P    = (float*)(ws + (size_t)(66) * (1 << 20));             // 4 MB
  float* prev = (float*)(ws + (size_t)(70) * (1 << 20));             // 256 KB

  transpose_w<<<dim3(32, 32), dim3(32, 32), 0, stream>>>(W, Wt);
  gemm_uhat<<<2048, 256, 0, stream>>>(x, Wt, uhat);

  route_partial<<<1024, 256, 0, stream>>>(uhat, prev, P, 1);
  route_reduce<<<1024, 64, 0, stream>>>(P, prev);
  route_partial<<<1024, 256, 0, stream>>>(uhat, prev, P, 0);
  route_reduce<<<1024, 64, 0, stream>>>(P, prev);
  route_partial<<<1024, 256, 0, stream>>>(uhat, prev, P, 0);
  route_reduce<<<1024, 64, 0, stream>>>(P, out);
}

// Round 3
// 342.801 us; speedup vs baseline: 1.1175x; 1.1175x over previous
//
#include <hip/hip_runtime.h>
#include <stdint.h>

#define NUM_CAP 16
#define DIM_CAP 64
#define BATCH   64
#define N_IN    512
#define D_IN    1024
#define N_COL   1024                 // NUM_CAP*DIM_CAP
#define M_ROWS  (BATCH*N_IN)         // 32768

typedef __attribute__((ext_vector_type(8))) short short8;
typedef __attribute__((ext_vector_type(4))) float f32x4;

__device__ __forceinline__ float bf2f(unsigned int u) {
  return __uint_as_float(u << 16);
}
__device__ __forceinline__ unsigned short f2bf_rne(float f) {
  unsigned int x = __float_as_uint(f);
  x += 0x7fffu + ((x >> 16) & 1u);   // RNE
  return (unsigned short)(x >> 16);
}
__device__ __forceinline__ unsigned int pack_rne(unsigned int lo, unsigned int hi) {
  const unsigned int lr = lo + (0x7fffu + ((lo >> 16) & 1u));
  const unsigned int hr = hi + (0x7fffu + ((hi >> 16) & 1u));
  return (lr >> 16) | (hr & 0xffff0000u);
}
__device__ __forceinline__ unsigned int pack_trunc(unsigned int lo, unsigned int hi) {
  return (lo >> 16) | (hi & 0xffff0000u);
}

// ---------------------------------------------------------------------------
// x fp32 -> bf16 (RNE), 8 elems/thread, fully coalesced.
// ---------------------------------------------------------------------------
__global__ __launch_bounds__(256) void conv_x(const float* __restrict__ x,
                                              unsigned short* __restrict__ xb) {
  const size_t i = ((size_t)blockIdx.x * 256 + threadIdx.x) * 8;
  const uint4 a = *(const uint4*)(x + i);
  const uint4 b = *(const uint4*)(x + i + 4);
  uint4 p;
  p.x = pack_rne(a.x, a.y); p.y = pack_rne(a.z, a.w);
  p.z = pack_rne(b.x, b.y); p.w = pack_rne(b.z, b.w);
  *(uint4*)(xb + i) = p;
}

// ---------------------------------------------------------------------------
// W fp32 [D_IN][N_COL] -> Wt bf16 [N_COL][D_IN]  (transpose + RNE convert)
// ---------------------------------------------------------------------------
__global__ void transpose_w(const float* __restrict__ W,
                            unsigned short* __restrict__ Wt) {
  __shared__ float tile[32][33];
  const int tx = threadIdx.x, ty = threadIdx.y;
  const int bx = blockIdx.x, by = blockIdx.y;
  tile[ty][tx] = W[(by * 32 + ty) * N_COL + bx * 32 + tx];
  __syncthreads();
  Wt[(bx * 32 + ty) * D_IN + by * 32 + tx] = f2bf_rne(tile[tx][ty]);
}

// ---------------------------------------------------------------------------
// PRIMARY GEMM: uhat[m][n] = sum_k xb[m][k] * Wt[n][k], all bf16 in HBM,
// both operands staged via global_load_lds width=16. XOR-swizzled LDS layout:
// position-chunk c of row r holds global chunk c ^ ((r>>1)&3)  -> fragment
// ds_read_b128 spreads over bank quads with only 2-way aliasing (free, m136).
// 128x128 tile, BK=32, 4 waves (2x2), each wave 4x4 of 16x16x32 MFMA.
// ---------------------------------------------------------------------------
__global__ __launch_bounds__(256) void gemm_uhat_b(
    const unsigned short* __restrict__ A,    // [M_ROWS][D_IN] bf16
    const unsigned short* __restrict__ Bt,   // [N_COL][D_IN] bf16
    unsigned short* __restrict__ C) {        // [M_ROWS][N_COL] bf16
  __shared__ __align__(16) unsigned short lA[128 * 32];
  __shared__ __align__(16) unsigned short lB[128 * 32];

  const int t = threadIdx.x;
  const int wave = t >> 6, lane = t & 63;
  const int mt = blockIdx.x >> 3, nt = blockIdx.x & 7;
  const int m0 = mt * 128, n0 = nt * 128;
  const int wm = wave & 1, wn = wave >> 1;

  f32x4 acc[4][4] = {};

  const int srow = lane >> 2;                              // row in 16-row segment
  const int schunk = ((lane & 3) ^ ((srow >> 1) & 3)) * 8; // swizzled 16B chunk

  for (int kt = 0; kt < D_IN / 32; ++kt) {
    const int k0 = kt * 32;
    __syncthreads();
    #pragma unroll
    for (int s0 = 0; s0 < 2; ++s0) {
      const int s = wave + s0 * 4;     // segment 0..7 (16 rows x 64B)
      const unsigned short* ga = A + (size_t)(m0 + s * 16 + srow) * D_IN + k0 + schunk;
      __builtin_amdgcn_global_load_lds(
          (const __attribute__((address_space(1))) void*)ga,
          (__attribute__((address_space(3))) void*)(lA + s * 512), 16, 0, 0);
      const unsigned short* gb = Bt + (size_t)(n0 + s * 16 + srow) * D_IN + k0 + schunk;
      __builtin_amdgcn_global_load_lds(
          (const __attribute__((address_space(1))) void*)gb,
          (__attribute__((address_space(3))) void*)(lB + s * 512), 16, 0, 0);
    }
    __syncthreads();

    short8 af[4], bfr[4];
    const int rsel = lane & 15;
    const int q = lane >> 4;
    const int koff = (q ^ ((rsel >> 1) & 3)) * 8;  // matching read swizzle
    #pragma unroll
    for (int tm = 0; tm < 4; tm++)
      af[tm] = *(const short8*)&lA[(wm * 64 + tm * 16 + rsel) * 32 + koff];
    #pragma unroll
    for (int tn = 0; tn < 4; tn++)
      bfr[tn] = *(const short8*)&lB[(wn * 64 + tn * 16 + rsel) * 32 + koff];
    #pragma unroll
    for (int tm = 0; tm < 4; tm++)
      #pragma unroll
      for (int tn = 0; tn < 4; tn++)
        acc[tm][tn] = __builtin_amdgcn_mfma_f32_16x16x32_bf16(
            af[tm], bfr[tn], acc[tm][tn], 0, 0, 0);
  }

  // Epilogue: C/D layout col=lane&15, row=(lane>>4)*4+reg  [m89-verified]
  const int lrow = (lane >> 4) * 4, lcol = lane & 15;
  #pragma unroll
  for (int tm = 0; tm < 4; tm++)
    #pragma unroll
    for (int tn = 0; tn < 4; tn++)
      #pragma unroll
      for (int r = 0; r < 4; r++) {
        const int row = m0 + wm * 64 + tm * 16 + lrow + r;
        const int col = n0 + wn * 64 + tn * 16 + lcol;
        C[(size_t)row * N_COL + col] = f2bf_rne(acc[tm][tn][r]);
      }
}

// ---------------------------------------------------------------------------
// FALLBACK GEMM (byte-identical logic to round-2 passing kernel): fp32 A
// staged via VALU pack. Used only if ws_size can't hold the bf16 copy of x.
// ---------------------------------------------------------------------------
#define LDA 40
__global__ __launch_bounds__(256) void gemm_uhat_f(
    const float* __restrict__ A,
    const unsigned short* __restrict__ Bt,
    unsigned short* __restrict__ C) {
  __shared__ __align__(16) unsigned short lA[128 * LDA];
  __shared__ __align__(16) unsigned short lB[128 * 32];

  const int t = threadIdx.x;
  const int wave = t >> 6, lane = t & 63;
  const int mt = blockIdx.x >> 3, nt = blockIdx.x & 7;
  const int m0 = mt * 128, n0 = nt * 128;
  const int wm = wave & 1, wn = wave >> 1;

  f32x4 acc[4][4] = {};

  const int ar = t >> 1, ah = t & 1;
  const float* agp = A + (size_t)(m0 + ar) * D_IN + ah * 16;
  unsigned short* lap = lA + ar * LDA + ah * 16;

  const int srow = lane >> 2;
  const int schunk = (lane & 3) * 8;

  for (int kt = 0; kt < D_IN / 32; ++kt) {
    const int k0 = kt * 32;
    __syncthreads();
    const uint4 a0 = *(const uint4*)(agp + k0);
    const uint4 a1 = *(const uint4*)(agp + k0 + 4);
    const uint4 a2 = *(const uint4*)(agp + k0 + 8);
    const uint4 a3 = *(const uint4*)(agp + k0 + 12);
    uint4 p0, p1;
    p0.x = pack_trunc(a0.x, a0.y); p0.y = pack_trunc(a0.z, a0.w);
    p0.z = pack_trunc(a1.x, a1.y); p0.w = pack_trunc(a1.z, a1.w);
    p1.x = pack_trunc(a2.x, a2.y); p1.y = pack_trunc(a2.z, a2.w);
    p1.z = pack_trunc(a3.x, a3.y); p1.w = pack_trunc(a3.z, a3.w);
    *(uint4*)lap       = p0;
    *(uint4*)(lap + 8) = p1;
    #pragma unroll
    for (int s0 = 0; s0 < 2; ++s0) {
      const int s = wave + s0 * 4;
      const unsigned short* gb = Bt + (size_t)(n0 + s * 16 + srow) * D_IN + k0 + schunk;
      __builtin_amdgcn_global_load_lds(
          (const __attribute__((address_space(1))) void*)gb,
          (__attribute__((address_space(3))) void*)(lB + s * 512), 16, 0, 0);
    }
    __syncthreads();

    short8 af[4], bfr[4];
    const int rsel = lane & 15;
    const int koff = (lane >> 4) * 8;
    #pragma unroll
    for (int tm = 0; tm < 4; tm++)
      af[tm] = *(const short8*)&lA[(wm * 64 + tm * 16 + rsel) * LDA + koff];
    #pragma unroll
    for (int tn = 0; tn < 4; tn++)
      bfr[tn] = *(const short8*)&lB[(wn * 64 + tn * 16 + rsel) * 32 + koff];
    #pragma unroll
    for (int tm = 0; tm < 4; tm++)
      #pragma unroll
      for (int tn = 0; tn < 4; tn++)
        acc[tm][tn] = __builtin_amdgcn_mfma_f32_16x16x32_bf16(
            af[tm], bfr[tn], acc[tm][tn], 0, 0, 0);
  }

  const int lrow = (lane >> 4) * 4, lcol = lane & 15;
  #pragma unroll
  for (int tm = 0; tm < 4; tm++)
    #pragma unroll
    for (int tn = 0; tn < 4; tn++)
      #pragma unroll
      for (int r = 0; r < 4; r++) {
        const int row = m0 + wm * 64 + tm * 16 + lrow + r;
        const int col = n0 + wn * 64 + tn * 16 + lcol;
        C[(size_t)row * N_COL + col] = f2bf_rne(acc[tm][tn][r]);
      }
}

// ---------------------------------------------------------------------------
// Routing pass: block = (b, jt4); wave w handles jt = jt4*4+w (8 j's).
// lane l holds u_hat[b, i=l>>2, j, k=(l&3)*16..+16]. Softmax over i via
// xor-{4..32} shuffles; block-reduce 4 waves via LDS -> P[b][jt4][i][k].
// ---------------------------------------------------------------------------
__global__ __launch_bounds__(256) void route_partial(
    const unsigned short* __restrict__ uhat,
    const float* __restrict__ prev,
    float* __restrict__ P,
    const int first) {
  __shared__ float red[4][1024];
  const int t = threadIdx.x;
  const int w = t >> 6, lane = t & 63;
  const int b = blockIdx.x >> 4, jt4 = blockIdx.x & 15;
  const int jt = jt4 * 4 + w;
  const int i_l = lane >> 2, c4 = lane & 3;

  float pv[16];
  if (!first) {
    const float* pp = prev + (b * NUM_CAP + i_l) * DIM_CAP + c4 * 16;
    #pragma unroll
    for (int q = 0; q < 16; q++) pv[q] = pp[q];
  }
  float acc[16];
  #pragma unroll
  for (int q = 0; q < 16; q++) acc[q] = 0.f;

  const unsigned short* ub =
      uhat + (size_t)(b * N_IN + jt * 8) * N_COL + lane * 16;

  for (int jj = 0; jj < 8; ++jj, ub += N_COL) {
    const uint4 d0 = *(const uint4*)ub;
    const uint4 d1 = *(const uint4*)(ub + 8);
    float u[16];
    #define UNP(wd, o) { u[(o)] = bf2f((wd) & 0xffffu); u[(o)+1] = __uint_as_float((wd) & 0xffff0000u); }
    UNP(d0.x, 0) UNP(d0.y, 2) UNP(d0.z, 4) UNP(d0.w, 6)
    UNP(d1.x, 8) UNP(d1.y, 10) UNP(d1.z, 12) UNP(d1.w, 14)
    #undef UNP

    float c;
    if (first) {
      c = 0.0625f;
    } else {
      float dot = 0.f;
      #pragma unroll
      for (int q = 0; q < 16; q++) dot = fmaf(pv[q], u[q], dot);
      dot += __shfl_xor(dot, 1);
      dot += __shfl_xor(dot, 2);
      float m = dot;
      #pragma unroll
      for (int d = 4; d < 64; d <<= 1) m = fmaxf(m, __shfl_xor(m, d));
      const float e = __expf(dot - m);
      float s = e;
      #pragma unroll
      for (int d = 4; d < 64; d <<= 1) s += __shfl_xor(s, d);
      c = e / s;
    }
    #pragma unroll
    for (int q = 0; q < 16; q++) acc[q] = fmaf(c, u[q], acc[q]);
  }

  #pragma unroll
  for (int q = 0; q < 4; q++)
    *(float4*)&red[w][lane * 16 + q * 4] = make_float4(
        acc[q * 4 + 0], acc[q * 4 + 1], acc[q * 4 + 2], acc[q * 4 + 3]);
  __syncthreads();
  const float4 r0 = *(const float4*)&red[0][t * 4];
  const float4 r1 = *(const float4*)&red[1][t * 4];
  const float4 r2 = *(const float4*)&red[2][t * 4];
  const float4 r3 = *(const float4*)&red[3][t * 4];
  float4 s;
  s.x = r0.x + r1.x + r2.x + r3.x;
  s.y = r0.y + r1.y + r2.y + r3.y;
  s.z = r0.z + r1.z + r2.z + r3.z;
  s.w = r0.w + r1.w + r2.w + r3.w;
  *(float4*)&P[(size_t)blockIdx.x * 1024 + t * 4] = s;
}

// ---------------------------------------------------------------------------
__global__ __launch_bounds__(64) void route_reduce(
    const float* __restrict__ P, float* __restrict__ dst) {
  const int bi = blockIdx.x;
  const int k = threadIdx.x;
  const int b = bi >> 4, i = bi & 15;
  const float* p = P + (size_t)b * 16 * 1024 + i * 64 + k;
  float s = 0.f;
  #pragma unroll
  for (int tt = 0; tt < 16; ++tt) s += p[(size_t)tt * 1024];
  float ss = s * s;
  #pragma unroll
  for (int d = 1; d < 64; d <<= 1) ss += __shfl_xor(ss, d);
  dst[bi * 64 + k] = s / sqrtf(ss + 1e-7f);
}

// ---------------------------------------------------------------------------
extern "C" void kernel_launch(void* const* d_in, const int* in_sizes, int n_in,
                              void* d_out, int out_size, void* d_ws, size_t ws_size,
                              hipStream_t stream) {
  const float* x = (const float*)d_in[0];   // [64][512][1024] fp32
  const float* W = (const float*)d_in[1];   // [1][1024][1024] fp32
  float* out = (float*)d_out;               // [64][16][64] fp32

  char* ws = (char*)d_ws;
  unsigned short* Wt   = (unsigned short*)ws;                        // 0..2 MB
  unsigned short* uhat = (unsigned short*)(ws + (size_t)(2 << 20));  // 2..66 MB
  float* P    = (float*)(ws + (size_t)66 * (1 << 20));               // 66..70 MB
  float* prev = (float*)(ws + (size_t)70 * (1 << 20));               // 70..70.25
  unsigned short* xb = (unsigned short*)(ws + (size_t)71 * (1 << 20)); // 71..135 MB

  transpose_w<<<dim3(32, 32), dim3(32, 32), 0, stream>>>(W, Wt);

  if (ws_size >= (size_t)135 * (1 << 20)) {
    conv_x<<<16384, 256, 0, stream>>>(x, xb);
    gemm_uhat_b<<<2048, 256, 0, stream>>>(xb, Wt, uhat);
  } else {
    gemm_uhat_f<<<2048, 256, 0, stream>>>(x, Wt, uhat);
  }

  route_partial<<<1024, 256, 0, stream>>>(uhat, prev, P, 1);
  route_reduce<<<1024, 64, 0, stream>>>(P, prev);
  route_partial<<<1024, 256, 0, stream>>>(uhat, prev, P, 0);
  route_reduce<<<1024, 64, 0, stream>>>(P, prev);
  route_partial<<<1024, 256, 0, stream>>>(uhat, prev, P, 0);
  route_reduce<<<1024, 64, 0, stream>>>(P, out);
}